// Round 7
// baseline (204.934 us; speedup 1.0000x reference)
//
#include <hip/hip_runtime.h>
#include <hip/hip_bf16.h>
#include <stdint.h>

// Problem sizes (fixed)
#define MROWS 4096   // batch B
#define LFULL 4096   // L
#define NHALF 2048   // N = L/2
#define HDIM  2048   // H

typedef __bf16 bf16x8 __attribute__((ext_vector_type(8)));
typedef float  f32x4  __attribute__((ext_vector_type(4)));
typedef unsigned short u16x8 __attribute__((ext_vector_type(8)));

__device__ __forceinline__ unsigned short f2bf(float f) {
    __hip_bfloat16 h = __float2bfloat16(f);
    return __builtin_bit_cast(unsigned short, h);
}
__device__ __forceinline__ float bf2f(unsigned short u) {
    return __builtin_bit_cast(float, (uint32_t)u << 16);
}
__device__ __forceinline__ float fast_tanh(float x) {
    float ax = fabsf(x);
    float e  = __expf(-2.0f * ax);
    float t  = (1.0f - e) / (1.0f + e);
    return copysignf(t, x);
}

__device__ __forceinline__ void gload_lds16(const void* g, void* l) {
    __builtin_amdgcn_global_load_lds(
        (const __attribute__((address_space(1))) uint32_t*)g,
        (__attribute__((address_space(3))) uint32_t*)l,
        16, 0, 0);
}

#define SBAR    __builtin_amdgcn_sched_barrier(0)
#define BARRIER do { SBAR; __builtin_amdgcn_s_barrier(); SBAR; } while (0)
#define LGKM0   do { asm volatile("s_waitcnt lgkmcnt(0)" ::: "memory"); SBAR; } while (0)

// ---------------------------------------------------------------------------
// Cast x even columns -> bf16 x_m (MROWS x NHALF)
// ---------------------------------------------------------------------------
__global__ __launch_bounds__(256)
void cast_x_kernel(const float* __restrict__ x, __hip_bfloat16* __restrict__ xm)
{
    size_t t = (size_t)blockIdx.x * 256 + threadIdx.x;
    size_t r = t >> 8;
    int    c = (int)(t & 255);
    const float4* xp = (const float4*)(x + r * LFULL + (size_t)c * 16);
    float4 a = xp[0], b = xp[1], d = xp[2], e = xp[3];
    u16x8 v;
    v[0] = f2bf(a.x); v[1] = f2bf(a.z);
    v[2] = f2bf(b.x); v[3] = f2bf(b.z);
    v[4] = f2bf(d.x); v[5] = f2bf(d.z);
    v[6] = f2bf(e.x); v[7] = f2bf(e.z);
    *(u16x8*)(xm + r * NHALF + (size_t)c * 8) = v;
}

// ---------------------------------------------------------------------------
// Transpose + cast: W (K x N, f32) -> WT (N x K, bf16)
// ---------------------------------------------------------------------------
__global__ __launch_bounds__(256)
void transpose_cast_kernel(const float* __restrict__ W, __hip_bfloat16* __restrict__ WT,
                           int K, int N)
{
    __shared__ unsigned short lds[64][66];
    const int t  = threadIdx.x;
    const int k0 = blockIdx.y * 64;
    const int n0 = blockIdx.x * 64;

    #pragma unroll
    for (int it = 0; it < 4; ++it) {
        int kl = it * 16 + (t >> 4);
        int nl = (t & 15) * 4;
        float4 v = *(const float4*)(W + (size_t)(k0 + kl) * N + n0 + nl);
        lds[kl][nl + 0] = f2bf(v.x);
        lds[kl][nl + 1] = f2bf(v.y);
        lds[kl][nl + 2] = f2bf(v.z);
        lds[kl][nl + 3] = f2bf(v.w);
    }
    __syncthreads();

    int nl = t >> 2;
    int kc = (t & 3) * 16;
    unsigned short tmp[16];
    #pragma unroll
    for (int j = 0; j < 16; ++j) tmp[j] = lds[kc + j][nl];
    u16x8* dst = (u16x8*)(WT + (size_t)(n0 + nl) * K + k0 + kc);
    dst[0] = *(u16x8*)&tmp[0];
    dst[1] = *(u16x8*)&tmp[8];
}

// ---------------------------------------------------------------------------
// m201-faithful 8-phase GEMM. A: MxKD bf16 row-major; BT: NOUT x KD bf16.
// 8 waves (2M x 4N), K-tile=64, 2 K-tiles per iter (buf0/buf1 compile-time).
// Each phase: {reads for this quad; stage 1 half-tile; BAR; lgkmcnt(0);
//              setprio(1); MFMA quad; setprio(0); BAR}.
// Quads per tile: p0=q00 p1=q01 p2=q10 p3=q11 (reads: 12/4/8/0).
// Stage slots (each region staged 1+ phase after its last reader, consumed
// 3-6 phases later): p0:A1(t1) p1:B1(t1) p2:B0(t0+2) p3:B1(t0+2)
//                    p4:A0(t0+2) p5:A1(t0+2) p6:B0(t1+2) p7:A0(t1+2)
// vmcnt(2*LB) at p3-end (gates t1's halves: prev-p6,prev-p7,p0,p1 landed);
// vmcnt(LB+LA) at p7-end (gates t0+2's halves: p2..p5 landed). Never 0
// except the tail iteration.
// ---------------------------------------------------------------------------
template<int BM, int BN, int KD, int NOUT, bool RELU>
__global__ __launch_bounds__(512, 2)
void gemm8p(const __hip_bfloat16* __restrict__ A,
            const __hip_bfloat16* __restrict__ BT,
            const float* __restrict__ bias,
            __hip_bfloat16* __restrict__ C)
{
    constexpr int MF = BM / 32, NF = BN / 64, MH = MF / 2, NH = NF / 2;
    constexpr int LA = BM / 128, LB = BN / 128;   // stage64 calls per half
    constexpr int NT = KD / 64;
    constexpr int ABYTES = BM * 128, BBYTES = BN * 128;
    constexpr int ABUF0 = 0, ABUF1 = ABYTES;
    constexpr int BBUF0 = 2 * ABYTES, BBUF1 = 2 * ABYTES + BBYTES;
    __shared__ __align__(1024) char lds[2 * ABYTES + 2 * BBYTES];

    const int tid  = threadIdx.x;
    const int wave = tid >> 6, lane = tid & 63;
    const int wm = wave >> 2, wn = wave & 3;
    const int l15 = lane & 15, lhi = lane >> 4;

    // XCD-aware bijective swizzle (grid multiple of 8)
    const int nwg = gridDim.x;
    const int bid = blockIdx.x;
    const int wg  = (bid & 7) * (nwg >> 3) + (bid >> 3);
    constexpr int NBN = NOUT / BN;
    const int bm = wg / NBN, bn = wg % NBN;

    const __hip_bfloat16* gA = A  + (size_t)(bm * BM) * KD;
    const __hip_bfloat16* gB = BT + (size_t)(bn * BN) * KD;

    // staging: row=tid>>3, 16B chunk=tid&7; source chunk XOR-swizzled by row&7
    const int srow = tid >> 3;
    const int scol = ((tid & 7) ^ (srow & 7)) * 8;   // elements
    char* sd = lds + srow * 128 + (tid & 7) * 16;    // linear LDS dest

    const __hip_bfloat16* pA = gA + (size_t)srow * KD + scol;
    const __hip_bfloat16* pB = gB + (size_t)srow * KD + scol;

    #define STAGE_A(HALF, KOFF, BUFOFF) { _Pragma("unroll") \
        for (int s = 0; s < LA; ++s) \
            gload_lds16(pA + (size_t)((HALF)*(BM/2) + s*64)*KD + (KOFF), \
                        sd + (BUFOFF) + (HALF)*(ABYTES/2) + s*8192); }
    #define STAGE_B(HALF, KOFF, BUFOFF) { _Pragma("unroll") \
        for (int s = 0; s < LB; ++s) \
            gload_lds16(pB + (size_t)((HALF)*(BN/2) + s*64)*KD + (KOFF), \
                        sd + (BUFOFF) + (HALF)*(BBYTES/2) + s*8192); }

    // ---- prologue: tile0 (4 halves) -> buf0; then B0,A0 of tile1 -> buf1
    STAGE_A(0, 0, ABUF0) STAGE_A(1, 0, ABUF0)
    STAGE_B(0, 0, BBUF0) STAGE_B(1, 0, BBUF0)
    STAGE_B(0, 64, BBUF1) STAGE_A(0, 64, ABUF1)
    asm volatile("s_waitcnt vmcnt(%0)" :: "n"(LB + LA) : "memory");
    SBAR;
    BARRIER;

    // ---- invariant per-lane LDS read bases (swizzle folds to (l15&7)<<4)
    const int arow0 = wm * (BM / 2) + l15;
    const int brow0 = wn * (BN / 4) + l15;
    const int swz   = (l15 & 7) << 4;
    const int colX[2] = { (lhi * 16) ^ swz, (64 + lhi * 16) ^ swz };
    const char* rA = lds + arow0 * 128;
    const char* rB = lds + brow0 * 128;

    bf16x8 af[MH][2], bf0[NH][2], bf1[NH][2];
    f32x4 acc[MF][NF] = {};

    #define READ_A(MHALF, BO) { _Pragma("unroll") \
        for (int m = 0; m < MH; ++m) { _Pragma("unroll") \
            for (int kk = 0; kk < 2; ++kk) \
                af[m][kk] = *(const bf16x8*)(rA + colX[kk] + ((BO) + ((MHALF)*MH + m)*2048)); } }
    #define READ_B(V, NHALF, BO) { _Pragma("unroll") \
        for (int n = 0; n < NH; ++n) { _Pragma("unroll") \
            for (int kk = 0; kk < 2; ++kk) \
                V[n][kk] = *(const bf16x8*)(rB + colX[kk] + ((BO) + ((NHALF)*NH + n)*2048)); } }
    #define MFMA_Q(MO, NO, BV) { \
        __builtin_amdgcn_s_setprio(1); _Pragma("unroll") \
        for (int kk = 0; kk < 2; ++kk) { _Pragma("unroll") \
            for (int m = 0; m < MH; ++m) { _Pragma("unroll") \
                for (int n = 0; n < NH; ++n) \
                    acc[(MO)+m][(NO)+n] = __builtin_amdgcn_mfma_f32_16x16x32_bf16( \
                        af[m][kk], BV[n][kk], acc[(MO)+m][(NO)+n], 0, 0, 0); } } \
        __builtin_amdgcn_s_setprio(0); }

    for (int t0 = 0; t0 < NT; t0 += 2) {
        const bool more = (t0 + 2 < NT);

        // ---- p0: reads a0,b0 (buf0); stage A1(t1)->buf1; q00
        READ_A(0, ABUF0) READ_B(bf0, 0, BBUF0)
        STAGE_A(1, 64, ABUF1)
        BARRIER; LGKM0;
        MFMA_Q(0, 0, bf0)
        BARRIER;

        // ---- p1: reads b1 (buf0); stage B1(t1)->buf1; q01
        READ_B(bf1, 1, BBUF0)
        STAGE_B(1, 64, BBUF1)
        BARRIER; LGKM0;
        MFMA_Q(0, NH, bf1)
        BARRIER;

        // ---- p2: reads a1 (buf0); stage B0(t0+2)->buf0; q10
        READ_A(1, ABUF0)
        if (more) STAGE_B(0, 128, BBUF0)
        BARRIER; LGKM0;
        MFMA_Q(MH, 0, bf0)
        BARRIER;

        // ---- p3: stage B1(t0+2)->buf0; q11; vmcnt gate for t1
        if (more) STAGE_B(1, 128, BBUF0)
        BARRIER;
        MFMA_Q(MH, NH, bf1)
        if (more) { asm volatile("s_waitcnt vmcnt(%0)" :: "n"(2 * LB) : "memory"); }
        else      { asm volatile("s_waitcnt vmcnt(0)" ::: "memory"); }
        SBAR;
        BARRIER;

        // ---- p4: reads a0,b0 (buf1); stage A0(t0+2)->buf0; q00 (tile t1)
        READ_A(0, ABUF1) READ_B(bf0, 0, BBUF1)
        if (more) STAGE_A(0, 128, ABUF0)
        BARRIER; LGKM0;
        MFMA_Q(0, 0, bf0)
        BARRIER;

        // ---- p5: reads b1 (buf1); stage A1(t0+2)->buf0; q01
        READ_B(bf1, 1, BBUF1)
        if (more) STAGE_A(1, 128, ABUF0)
        BARRIER; LGKM0;
        MFMA_Q(0, NH, bf1)
        BARRIER;

        // ---- p6: reads a1 (buf1); stage B0(t1+2)->buf1; q10
        READ_A(1, ABUF1)
        if (more) STAGE_B(0, 192, BBUF1)
        BARRIER; LGKM0;
        MFMA_Q(MH, 0, bf0)
        BARRIER;

        // ---- p7: stage A0(t1+2)->buf1; q11; vmcnt gate for t0+2
        if (more) STAGE_A(0, 192, ABUF1)
        BARRIER;
        MFMA_Q(MH, NH, bf1)
        asm volatile("s_waitcnt vmcnt(%0)" :: "n"(LB + LA) : "memory");
        SBAR;
        BARRIER;

        pA += 128; pB += 128;
    }

    #undef STAGE_A
    #undef STAGE_B
    #undef READ_A
    #undef READ_B
    #undef MFMA_Q

    // ---- C write: col = lane&15 (+n*16), row = lhi*4 + r (+m*16)
    const int crow0 = bm * BM + wm * (BM / 2) + lhi * 4;
    const int ccol0 = bn * BN + wn * (BN / 4) + l15;
    #pragma unroll
    for (int m = 0; m < MF; ++m) {
        #pragma unroll
        for (int n = 0; n < NF; ++n) {
            int col = ccol0 + n * 16;
            float bv = bias[col];
            #pragma unroll
            for (int r = 0; r < 4; ++r) {
                int row = crow0 + m * 16 + r;
                float v = acc[m][n][r] + bv;
                if (RELU) v = (v > 0.0f) ? v : 0.2f * v;
                C[(size_t)row * NOUT + col] = __float2bfloat16(v);
            }
        }
    }
}

// ---------------------------------------------------------------------------
// Epilogue: s/t split, y assembly, per-row log_det
// ---------------------------------------------------------------------------
__global__ __launch_bounds__(256)
void epilogue_kernel(const float* __restrict__ x,
                     const __hip_bfloat16* __restrict__ outb,
                     float* __restrict__ y, float* __restrict__ ld)
{
    const int i = blockIdx.x;
    const int t = threadIdx.x;
    const __hip_bfloat16* orow = outb + (size_t)i * LFULL;
    const float* xrow = x + (size_t)i * LFULL;
    float* yrow = y + (size_t)i * LFULL;

    const int j0 = t * 8;
    u16x8 sv = *(const u16x8*)(orow + j0);
    u16x8 tv = *(const u16x8*)(orow + NHALF + j0);

    float part = 0.0f;
    #pragma unroll
    for (int u = 0; u < 8; u += 2) {
        float4 xv = *(const float4*)(xrow + 2 * (j0 + u));
        float s0 = bf2f(sv[u]),     s1 = bf2f(sv[u + 1]);
        float t0 = bf2f(tv[u]),     t1 = bf2f(tv[u + 1]);
        float a0 = 2.0f * fast_tanh(s0);
        float a1 = 2.0f * fast_tanh(s1);
        part += a0 + a1;
        float4 yv;
        yv.x = xv.x;  yv.y = xv.y * __expf(a0) + t0;
        yv.z = xv.z;  yv.w = xv.w * __expf(a1) + t1;
        *(float4*)(yrow + 2 * (j0 + u)) = yv;
    }

    #pragma unroll
    for (int off = 32; off; off >>= 1) part += __shfl_down(part, off, 64);
    __shared__ float red[4];
    if ((t & 63) == 0) red[t >> 6] = part;
    __syncthreads();
    if (t == 0) ld[i] = red[0] + red[1] + red[2] + red[3];
}

// ---------------------------------------------------------------------------
extern "C" void kernel_launch(void* const* d_in, const int* in_sizes, int n_in,
                              void* d_out, int out_size, void* d_ws, size_t ws_size,
                              hipStream_t stream)
{
    const float* x  = (const float*)d_in[0];
    const float* W1 = (const float*)d_in[1];
    const float* b1 = (const float*)d_in[2];
    const float* W2 = (const float*)d_in[3];
    const float* b2 = (const float*)d_in[4];
    const float* W3 = (const float*)d_in[5];
    const float* b3 = (const float*)d_in[6];

    char* ws = (char*)d_ws;
    const size_t MB = 1u << 20;
    __hip_bfloat16* W3T  = (__hip_bfloat16*)(ws);              // 16 MB: 4096x2048
    __hip_bfloat16* h2   = (__hip_bfloat16*)(ws + 16 * MB);    // 16 MB: 4096x2048
    __hip_bfloat16* xmb  = (__hip_bfloat16*)(ws + 32 * MB);    // 16 MB
    __hip_bfloat16* W1T  = (__hip_bfloat16*)(ws + 48 * MB);    //  8 MB
    __hip_bfloat16* W2T  = (__hip_bfloat16*)(ws + 56 * MB);    //  8 MB
    __hip_bfloat16* h1   = (__hip_bfloat16*)(ws + 64 * MB);    // 16 MB
    __hip_bfloat16* outb = (__hip_bfloat16*)(ws + 32 * MB);    // 32 MB (overlays xmb/W1T/W2T)

    float* y  = (float*)d_out;
    float* ld = y + (size_t)MROWS * LFULL;

    cast_x_kernel<<<4096, 256, 0, stream>>>(x, xmb);
    transpose_cast_kernel<<<dim3(32, 32), 256, 0, stream>>>(W1, W1T, HDIM, HDIM);
    transpose_cast_kernel<<<dim3(32, 32), 256, 0, stream>>>(W2, W2T, HDIM, HDIM);
    transpose_cast_kernel<<<dim3(64, 32), 256, 0, stream>>>(W3, W3T, HDIM, LFULL);

    gemm8p<128, 256, 2048, 2048, true ><<<dim3(256), dim3(512), 0, stream>>>(xmb, W1T, b1, h1);
    gemm8p<128, 256, 2048, 2048, true ><<<dim3(256), dim3(512), 0, stream>>>(h1,  W2T, b2, h2);
    gemm8p<256, 256, 2048, 4096, false><<<dim3(256), dim3(512), 0, stream>>>(h2,  W3T, b3, outb);

    epilogue_kernel<<<4096, 256, 0, stream>>>(x, outb, y, ld);
}

// Round 8
// 184.844 us; speedup vs baseline: 1.1087x; 1.1087x over previous
//
#include <hip/hip_runtime.h>
#include <hip/hip_bf16.h>
#include <stdint.h>

// Problem sizes (fixed)
#define MROWS 4096   // batch B
#define LFULL 4096   // L
#define NHALF 2048   // N = L/2
#define HDIM  2048   // H

typedef __bf16 bf16x8 __attribute__((ext_vector_type(8)));
typedef float  f32x4  __attribute__((ext_vector_type(4)));
typedef unsigned short u16x8 __attribute__((ext_vector_type(8)));

template<int V> struct ICt { static constexpr int value = V; };

__device__ __forceinline__ unsigned short f2bf(float f) {
    __hip_bfloat16 h = __float2bfloat16(f);
    return __builtin_bit_cast(unsigned short, h);
}
__device__ __forceinline__ float bf2f(unsigned short u) {
    return __builtin_bit_cast(float, (uint32_t)u << 16);
}
__device__ __forceinline__ float fast_tanh(float x) {
    float ax = fabsf(x);
    float e  = __expf(-2.0f * ax);
    float t  = (1.0f - e) / (1.0f + e);
    return copysignf(t, x);
}

__device__ __forceinline__ void gload_lds16(const void* g, void* l) {
    __builtin_amdgcn_global_load_lds(
        (const __attribute__((address_space(1))) uint32_t*)g,
        (__attribute__((address_space(3))) uint32_t*)l,
        16, 0, 0);
}

// ---------------------------------------------------------------------------
// Cast x even columns -> bf16 x_m; also zero ld (GEMM3 accumulates atomically)
// ---------------------------------------------------------------------------
__global__ __launch_bounds__(256)
void cast_x_kernel(const float* __restrict__ x, __hip_bfloat16* __restrict__ xm,
                   float* __restrict__ ld)
{
    if (threadIdx.x == 0) ld[blockIdx.x] = 0.0f;
    size_t t = (size_t)blockIdx.x * 256 + threadIdx.x;
    size_t r = t >> 8;
    int    c = (int)(t & 255);
    const float4* xp = (const float4*)(x + r * LFULL + (size_t)c * 16);
    float4 a = xp[0], b = xp[1], d = xp[2], e = xp[3];
    u16x8 v;
    v[0] = f2bf(a.x); v[1] = f2bf(a.z);
    v[2] = f2bf(b.x); v[3] = f2bf(b.z);
    v[4] = f2bf(d.x); v[5] = f2bf(d.z);
    v[6] = f2bf(e.x); v[7] = f2bf(e.z);
    *(u16x8*)(xm + r * NHALF + (size_t)c * 8) = v;
}

// ---------------------------------------------------------------------------
// Transpose + cast: W (K x N, f32) -> WT (N x K, bf16).
// PERM (for W3): route true-col jc to permuted row so GEMM3's block bn holds
// cols {bn*128..+127} and {2048+bn*128..+127} with s-frag n paired to
// t-frag n+2 (same lane/row/reg).
// ---------------------------------------------------------------------------
template<bool PERM>
__global__ __launch_bounds__(256)
void transpose_cast_kernel(const float* __restrict__ W, __hip_bfloat16* __restrict__ WT,
                           int K, int N)
{
    __shared__ unsigned short lds[64][66];
    const int t  = threadIdx.x;
    const int k0 = blockIdx.y * 64;
    const int n0 = blockIdx.x * 64;

    #pragma unroll
    for (int it = 0; it < 4; ++it) {
        int kl = it * 16 + (t >> 4);
        int nl = (t & 15) * 4;
        float4 v = *(const float4*)(W + (size_t)(k0 + kl) * N + n0 + nl);
        lds[kl][nl + 0] = f2bf(v.x);
        lds[kl][nl + 1] = f2bf(v.y);
        lds[kl][nl + 2] = f2bf(v.z);
        lds[kl][nl + 3] = f2bf(v.w);
    }
    __syncthreads();

    int nl = t >> 2;
    int kc = (t & 3) * 16;
    unsigned short tmp[16];
    #pragma unroll
    for (int j = 0; j < 16; ++j) tmp[j] = lds[kc + j][nl];
    int jc = n0 + nl;
    int dstrow;
    if (PERM) {
        int half = jc >> 11;          // 0 = s-col, 1 = t-col
        int j    = jc & 2047;
        int g = j >> 7, w = j & 127;
        int q = w >> 5, rest = w & 31, f = rest >> 4, c = rest & 15;
        dstrow = g * 256 + q * 64 + (f + 2 * half) * 16 + c;
    } else {
        dstrow = jc;
    }
    u16x8* dst = (u16x8*)(WT + (size_t)dstrow * K + k0 + kc);
    dst[0] = *(u16x8*)&tmp[0];
    dst[1] = *(u16x8*)&tmp[8];
}

// ---------------------------------------------------------------------------
// 8-phase GEMM, counted-wait pipelined (R6 structure, verbatim K-loop).
// FUSED (GEMM3): no C write; instead s/t pairing in-register, y odd-col
// update + even-col passthrough (float2), per-row log_det atomics.
// ---------------------------------------------------------------------------
template<int BM, int BN, int KD, int NOUT, bool RELU, bool FUSED>
__global__ __launch_bounds__(512, 2)
void gemm8p(const __hip_bfloat16* __restrict__ A,
            const __hip_bfloat16* __restrict__ BT,
            const float* __restrict__ bias,
            __hip_bfloat16* __restrict__ C,
            const float* __restrict__ xg,
            float* __restrict__ yg,
            float* __restrict__ ldg)
{
    constexpr int MF = BM / 32, NF = BN / 64, MH = MF / 2, NH = NF / 2;
    constexpr int LA = BM / 128, LB = BN / 128;
    constexpr int NT = KD / 64;
    constexpr int ABYTES = BM * 128, BBYTES = BN * 128;
    constexpr int BBASE = 2 * ABYTES;
    __shared__ __align__(1024) char lds[2 * ABYTES + 2 * BBYTES];

    const int tid  = threadIdx.x;
    const int wave = tid >> 6, lane = tid & 63;
    const int wm = wave >> 2, wn = wave & 3;
    const int l15 = lane & 15, lhi = lane >> 4;

    // XCD-aware bijective swizzle (grid multiple of 8)
    const int nwg = gridDim.x;
    const int bid = blockIdx.x;
    const int wg  = (bid & 7) * (nwg >> 3) + (bid >> 3);
    constexpr int NBN = NOUT / BN;
    const int bm = wg / NBN, bn = wg % NBN;

    const __hip_bfloat16* gA = A  + (size_t)(bm * BM) * KD;
    const __hip_bfloat16* gB = BT + (size_t)(bn * BN) * KD;

    // staging: row=tid>>3, 16B chunk=tid&7; source chunk XOR-swizzled by row&7
    const int srow = tid >> 3;
    const int scol = ((tid & 7) ^ (srow & 7)) * 8;   // elements
    char* sd = lds + srow * 128 + (tid & 7) * 16;    // linear LDS dest

    const __hip_bfloat16* pA = gA + (size_t)srow * KD + scol;
    const __hip_bfloat16* pB = gB + (size_t)srow * KD + scol;

    // ---- prologue: B(0)->Bbuf0, A(0)->Abuf0, B(1)->Bbuf1
    #pragma unroll
    for (int s = 0; s < LB; ++s) gload_lds16(pB + (size_t)(s * 64) * KD,             sd + BBASE + s * 8192);
    #pragma unroll
    for (int s = 0; s < LB; ++s) gload_lds16(pB + (size_t)(BN/2 + s * 64) * KD,      sd + BBASE + (BN/2) * 128 + s * 8192);
    #pragma unroll
    for (int s = 0; s < LA; ++s) gload_lds16(pA + (size_t)(s * 64) * KD,             sd + s * 8192);
    #pragma unroll
    for (int s = 0; s < LA; ++s) gload_lds16(pA + (size_t)(BM/2 + s * 64) * KD,      sd + (BM/2) * 128 + s * 8192);
    #pragma unroll
    for (int s = 0; s < LB; ++s) gload_lds16(pB + 64 + (size_t)(s * 64) * KD,        sd + BBASE + BBYTES + s * 8192);
    #pragma unroll
    for (int s = 0; s < LB; ++s) gload_lds16(pB + 64 + (size_t)(BN/2 + s * 64) * KD, sd + BBASE + BBYTES + (BN/2) * 128 + s * 8192);
    pA += 64; pB += 128;
    asm volatile("s_waitcnt vmcnt(4)" ::: "memory");
    __builtin_amdgcn_s_barrier();

    // ---- invariant per-lane LDS read bases (swizzle folds to (l15&7)<<4)
    const int arow0 = wm * (BM / 2) + l15;
    const int brow0 = wn * (BN / 4) + l15;
    const int swz   = (l15 & 7) << 4;
    const int colX[2] = { (lhi * 16) ^ swz, (64 + lhi * 16) ^ swz };
    const char* rA = lds + arow0 * 128;
    const char* rB = lds + brow0 * 128;

    bf16x8 af[MH][2], bf0[NH][2], bf1[NH][2];
    f32x4 acc[MF][NF] = {};

    // pre-read aLO(0), bLO(0)
    #pragma unroll
    for (int m = 0; m < MH; ++m)
        #pragma unroll
        for (int kk = 0; kk < 2; ++kk)
            af[m][kk] = *(const bf16x8*)(rA + colX[kk] + m * 2048);
    #pragma unroll
    for (int n = 0; n < NH; ++n)
        #pragma unroll
        for (int kk = 0; kk < 2; ++kk)
            bf0[n][kk] = *(const bf16x8*)(rB + colX[kk] + (BBASE + n * 2048));

    auto body = [&](int t, auto bufc) {
        constexpr int BUF   = decltype(bufc)::value;
        constexpr int ABUF  = BUF * ABYTES;
        constexpr int ABUFo = (BUF ^ 1) * ABYTES;
        constexpr int BBUF  = BBASE + BUF * BBYTES;
        constexpr int BBUFo = BBASE + (BUF ^ 1) * BBYTES;

        // ---- P0: stage A0(t+1); MFMA q00; read bHI(t)
        if (t + 1 < NT) {
            #pragma unroll
            for (int s = 0; s < LA; ++s)
                gload_lds16(pA + (size_t)(s * 64) * KD, sd + ABUFo + s * 8192);
        }
        __builtin_amdgcn_s_setprio(1);
        #pragma unroll
        for (int kk = 0; kk < 2; ++kk)
            #pragma unroll
            for (int m = 0; m < MH; ++m)
                #pragma unroll
                for (int n = 0; n < NH; ++n)
                    acc[m][n] = __builtin_amdgcn_mfma_f32_16x16x32_bf16(af[m][kk], bf0[n][kk], acc[m][n], 0, 0, 0);
        __builtin_amdgcn_s_setprio(0);
        #pragma unroll
        for (int n = 0; n < NH; ++n)
            #pragma unroll
            for (int kk = 0; kk < 2; ++kk)
                bf1[n][kk] = *(const bf16x8*)(rB + colX[kk] + (BBUF + (NH + n) * 2048));
        __builtin_amdgcn_s_barrier();

        // ---- P1: stage A1(t+1); MFMA q01; read aHI(t)
        if (t + 1 < NT) {
            #pragma unroll
            for (int s = 0; s < LA; ++s)
                gload_lds16(pA + (size_t)(BM/2 + s * 64) * KD, sd + ABUFo + (BM/2) * 128 + s * 8192);
        }
        __builtin_amdgcn_s_setprio(1);
        #pragma unroll
        for (int kk = 0; kk < 2; ++kk)
            #pragma unroll
            for (int m = 0; m < MH; ++m)
                #pragma unroll
                for (int n = 0; n < NH; ++n)
                    acc[m][NH + n] = __builtin_amdgcn_mfma_f32_16x16x32_bf16(af[m][kk], bf1[n][kk], acc[m][NH + n], 0, 0, 0);
        __builtin_amdgcn_s_setprio(0);
        #pragma unroll
        for (int m = 0; m < MH; ++m)
            #pragma unroll
            for (int kk = 0; kk < 2; ++kk)
                af[m][kk] = *(const bf16x8*)(rA + colX[kk] + (ABUF + (MH + m) * 2048));
        __builtin_amdgcn_s_barrier();

        // ---- P2: stage B0(t+2); MFMA q10
        if (t + 2 < NT) {
            #pragma unroll
            for (int s = 0; s < LB; ++s)
                gload_lds16(pB + (size_t)(s * 64) * KD, sd + BBUF + s * 8192);
        }
        __builtin_amdgcn_s_setprio(1);
        #pragma unroll
        for (int kk = 0; kk < 2; ++kk)
            #pragma unroll
            for (int m = 0; m < MH; ++m)
                #pragma unroll
                for (int n = 0; n < NH; ++n)
                    acc[MH + m][n] = __builtin_amdgcn_mfma_f32_16x16x32_bf16(af[m][kk], bf0[n][kk], acc[MH + m][n], 0, 0, 0);
        __builtin_amdgcn_s_setprio(0);
        __builtin_amdgcn_s_barrier();

        // ---- P3: stage B1(t+2); vmcnt; tile-boundary barrier;
        //          read bLO(t+1); MFMA q11; read aLO(t+1)
        if (t + 2 < NT) {
            #pragma unroll
            for (int s = 0; s < LB; ++s)
                gload_lds16(pB + (size_t)(BN/2 + s * 64) * KD, sd + BBUF + (BN/2) * 128 + s * 8192);
            asm volatile("s_waitcnt vmcnt(4)" ::: "memory");
        } else {
            asm volatile("s_waitcnt vmcnt(0)" ::: "memory");
        }
        __builtin_amdgcn_s_barrier();
        if (t + 1 < NT) {
            #pragma unroll
            for (int n = 0; n < NH; ++n)
                #pragma unroll
                for (int kk = 0; kk < 2; ++kk)
                    bf0[n][kk] = *(const bf16x8*)(rB + colX[kk] + (BBUFo + n * 2048));
        }
        __builtin_amdgcn_s_setprio(1);
        #pragma unroll
        for (int kk = 0; kk < 2; ++kk)
            #pragma unroll
            for (int m = 0; m < MH; ++m)
                #pragma unroll
                for (int n = 0; n < NH; ++n)
                    acc[MH + m][NH + n] = __builtin_amdgcn_mfma_f32_16x16x32_bf16(af[m][kk], bf1[n][kk], acc[MH + m][NH + n], 0, 0, 0);
        __builtin_amdgcn_s_setprio(0);
        if (t + 1 < NT) {
            #pragma unroll
            for (int m = 0; m < MH; ++m)
                #pragma unroll
                for (int kk = 0; kk < 2; ++kk)
                    af[m][kk] = *(const bf16x8*)(rA + colX[kk] + (ABUFo + m * 2048));
        }
        pA += 64; pB += 64;
    };

    for (int tt = 0; tt < NT; tt += 2) {
        body(tt,     ICt<0>{});
        body(tt + 1, ICt<1>{});
    }

    if constexpr (FUSED) {
        // acc frag n in {0,1} = s_j, frag n+2 = t_j (same lane/row/reg),
        // j = bn*128 + wn*32 + n*16 + l15 (W3 was PERM-transposed).
        const int crow0 = bm * BM + wm * (BM / 2) + lhi * 4;
        const int jbase = bn * (BN / 2) + wn * 32 + l15;
        #pragma unroll
        for (int m = 0; m < MF; ++m) {
            #pragma unroll
            for (int r = 0; r < 4; ++r) {
                const int row = crow0 + m * 16 + r;
                float ldp = 0.0f;
                #pragma unroll
                for (int n = 0; n < 2; ++n) {
                    const int j = jbase + n * 16;
                    float sval = acc[m][n][r]     + bias[j];
                    float tval = acc[m][n + 2][r] + bias[NHALF + j];
                    float a = 2.0f * fast_tanh(sval);
                    ldp += a;
                    float2 xv = *(const float2*)(xg + (size_t)row * LFULL + 2 * j);
                    float2 yv;
                    yv.x = xv.x;                       // even col: exact copy
                    yv.y = xv.y * __expf(a) + tval;    // odd col: affine update
                    *(float2*)(yg + (size_t)row * LFULL + 2 * j) = yv;
                }
                ldp += __shfl_xor(ldp, 1, 64);
                ldp += __shfl_xor(ldp, 2, 64);
                ldp += __shfl_xor(ldp, 4, 64);
                ldp += __shfl_xor(ldp, 8, 64);
                if (l15 == 0) atomicAdd(&ldg[row], ldp);
            }
        }
    } else {
        // ---- C write: col = lane&15 (+n*16), row = lhi*4 + r (+m*16)
        const int crow0 = bm * BM + wm * (BM / 2) + lhi * 4;
        const int ccol0 = bn * BN + wn * (BN / 4) + l15;
        #pragma unroll
        for (int m = 0; m < MF; ++m) {
            #pragma unroll
            for (int n = 0; n < NF; ++n) {
                int col = ccol0 + n * 16;
                float bv = bias[col];
                #pragma unroll
                for (int r = 0; r < 4; ++r) {
                    int row = crow0 + m * 16 + r;
                    float v = acc[m][n][r] + bv;
                    if (RELU) v = (v > 0.0f) ? v : 0.2f * v;
                    C[(size_t)row * NOUT + col] = __float2bfloat16(v);
                }
            }
        }
    }
}

// ---------------------------------------------------------------------------
extern "C" void kernel_launch(void* const* d_in, const int* in_sizes, int n_in,
                              void* d_out, int out_size, void* d_ws, size_t ws_size,
                              hipStream_t stream)
{
    const float* x  = (const float*)d_in[0];
    const float* W1 = (const float*)d_in[1];
    const float* b1 = (const float*)d_in[2];
    const float* W2 = (const float*)d_in[3];
    const float* b2 = (const float*)d_in[4];
    const float* W3 = (const float*)d_in[5];
    const float* b3 = (const float*)d_in[6];

    char* ws = (char*)d_ws;
    const size_t MB = 1u << 20;
    __hip_bfloat16* W3T  = (__hip_bfloat16*)(ws);              // 16 MB: 4096x2048 (PERM)
    __hip_bfloat16* h2   = (__hip_bfloat16*)(ws + 16 * MB);    // 16 MB: 4096x2048
    __hip_bfloat16* xmb  = (__hip_bfloat16*)(ws + 32 * MB);    // 16 MB
    __hip_bfloat16* W1T  = (__hip_bfloat16*)(ws + 48 * MB);    //  8 MB
    __hip_bfloat16* W2T  = (__hip_bfloat16*)(ws + 56 * MB);    //  8 MB
    __hip_bfloat16* h1   = (__hip_bfloat16*)(ws + 64 * MB);    // 16 MB

    float* y  = (float*)d_out;
    float* ld = y + (size_t)MROWS * LFULL;

    cast_x_kernel<<<4096, 256, 0, stream>>>(x, xmb, ld);
    transpose_cast_kernel<false><<<dim3(32, 32), 256, 0, stream>>>(W1, W1T, HDIM, HDIM);
    transpose_cast_kernel<false><<<dim3(32, 32), 256, 0, stream>>>(W2, W2T, HDIM, HDIM);
    transpose_cast_kernel<true ><<<dim3(64, 32), 256, 0, stream>>>(W3, W3T, HDIM, LFULL);

    gemm8p<128, 256, 2048, 2048, true,  false><<<dim3(256), dim3(512), 0, stream>>>(xmb, W1T, b1, h1, nullptr, nullptr, nullptr);
    gemm8p<128, 256, 2048, 2048, true,  false><<<dim3(256), dim3(512), 0, stream>>>(h1,  W2T, b2, h2, nullptr, nullptr, nullptr);
    gemm8p<256, 256, 2048, 4096, false, true ><<<dim3(256), dim3(512), 0, stream>>>(h2,  W3T, b3, nullptr, x, y, ld);
}

// Round 9
// 181.846 us; speedup vs baseline: 1.1270x; 1.0165x over previous
//
#include <hip/hip_runtime.h>
#include <hip/hip_bf16.h>
#include <stdint.h>

// Problem sizes (fixed)
#define MROWS 4096   // batch B
#define LFULL 4096   // L
#define NHALF 2048   // N = L/2
#define HDIM  2048   // H

typedef __bf16 bf16x8 __attribute__((ext_vector_type(8)));
typedef float  f32x4  __attribute__((ext_vector_type(4)));
typedef unsigned short u16x8 __attribute__((ext_vector_type(8)));

template<int V> struct ICt { static constexpr int value = V; };

__device__ __forceinline__ unsigned short f2bf(float f) {
    __hip_bfloat16 h = __float2bfloat16(f);
    return __builtin_bit_cast(unsigned short, h);
}
__device__ __forceinline__ float bf2f(unsigned short u) {
    return __builtin_bit_cast(float, (uint32_t)u << 16);
}
__device__ __forceinline__ float fast_tanh(float x) {
    float ax = fabsf(x);
    float e  = __expf(-2.0f * ax);
    float t  = (1.0f - e) / (1.0f + e);
    return copysignf(t, x);
}

__device__ __forceinline__ void gload_lds16(const void* g, void* l) {
    __builtin_amdgcn_global_load_lds(
        (const __attribute__((address_space(1))) uint32_t*)g,
        (__attribute__((address_space(3))) uint32_t*)l,
        16, 0, 0);
}

// ---------------------------------------------------------------------------
// Cast x even columns -> bf16 x_m; also zero ld (GEMM3 accumulates atomically)
// ---------------------------------------------------------------------------
__global__ __launch_bounds__(256)
void cast_x_kernel(const float* __restrict__ x, __hip_bfloat16* __restrict__ xm,
                   float* __restrict__ ld)
{
    if (threadIdx.x == 0) ld[blockIdx.x] = 0.0f;
    size_t t = (size_t)blockIdx.x * 256 + threadIdx.x;
    size_t r = t >> 8;
    int    c = (int)(t & 255);
    const float4* xp = (const float4*)(x + r * LFULL + (size_t)c * 16);
    float4 a = xp[0], b = xp[1], d = xp[2], e = xp[3];
    u16x8 v;
    v[0] = f2bf(a.x); v[1] = f2bf(a.z);
    v[2] = f2bf(b.x); v[3] = f2bf(b.z);
    v[4] = f2bf(d.x); v[5] = f2bf(d.z);
    v[6] = f2bf(e.x); v[7] = f2bf(e.z);
    *(u16x8*)(xm + r * NHALF + (size_t)c * 8) = v;
}

// ---------------------------------------------------------------------------
// Transpose + cast: W (K x N, f32) -> WT (N x K, bf16).
// PERM (for W3): route true-col jc so GEMM3's block bn holds cols
// {bn*128..+127} and {2048+bn*128..+127}, s-frag n paired with t-frag n+2.
// ---------------------------------------------------------------------------
template<bool PERM>
__global__ __launch_bounds__(256)
void transpose_cast_kernel(const float* __restrict__ W, __hip_bfloat16* __restrict__ WT,
                           int K, int N)
{
    __shared__ unsigned short lds[64][66];
    const int t  = threadIdx.x;
    const int k0 = blockIdx.y * 64;
    const int n0 = blockIdx.x * 64;

    #pragma unroll
    for (int it = 0; it < 4; ++it) {
        int kl = it * 16 + (t >> 4);
        int nl = (t & 15) * 4;
        float4 v = *(const float4*)(W + (size_t)(k0 + kl) * N + n0 + nl);
        lds[kl][nl + 0] = f2bf(v.x);
        lds[kl][nl + 1] = f2bf(v.y);
        lds[kl][nl + 2] = f2bf(v.z);
        lds[kl][nl + 3] = f2bf(v.w);
    }
    __syncthreads();

    int nl = t >> 2;
    int kc = (t & 3) * 16;
    unsigned short tmp[16];
    #pragma unroll
    for (int j = 0; j < 16; ++j) tmp[j] = lds[kc + j][nl];
    int jc = n0 + nl;
    int dstrow;
    if (PERM) {
        int half = jc >> 11;          // 0 = s-col, 1 = t-col
        int j    = jc & 2047;
        int g = j >> 7, w = j & 127;
        int q = w >> 5, rest = w & 31, f = rest >> 4, c = rest & 15;
        dstrow = g * 256 + q * 64 + (f + 2 * half) * 16 + c;
    } else {
        dstrow = jc;
    }
    u16x8* dst = (u16x8*)(WT + (size_t)dstrow * K + k0 + kc);
    dst[0] = *(u16x8*)&tmp[0];
    dst[1] = *(u16x8*)&tmp[8];
}

// ---------------------------------------------------------------------------
// 8-phase GEMM, counted-wait pipelined, MINIMAL BARRIERS (2 per K-tile).
// Barrier ledger (cross-wave read->overwrite pairs, each needs >=1 barrier):
//   bHI(t) read P0 / aHI(t) read P1  vs  B(t+2)/A-buf overwrite P2+/next-P0:
//       protected by P1-end barrier.
//   aLO/bLO(t+1) reads P3-end  vs  stages into that buffer at t+1's P0+:
//       protected by P3 post-vmcnt barrier (+ next P1 barrier).
//   vmcnt(4) per-wave at P3 + the P3 barrier publish A(t+1),B(t+1) for all.
// P0-end / P2-end barriers removed: waves drift across phases -> one wave's
// lgkm/vmem stall overlaps another's MFMA cluster (m114 TLP mechanism).
// FUSED (GEMM3): s/t pairing in-register, y float2 write, log_det atomics.
// ---------------------------------------------------------------------------
template<int BM, int BN, int KD, int NOUT, bool RELU, bool FUSED>
__global__ __launch_bounds__(512, 2)
void gemm8p(const __hip_bfloat16* __restrict__ A,
            const __hip_bfloat16* __restrict__ BT,
            const float* __restrict__ bias,
            __hip_bfloat16* __restrict__ C,
            const float* __restrict__ xg,
            float* __restrict__ yg,
            float* __restrict__ ldg)
{
    constexpr int MF = BM / 32, NF = BN / 64, MH = MF / 2, NH = NF / 2;
    constexpr int LA = BM / 128, LB = BN / 128;
    constexpr int NT = KD / 64;
    constexpr int ABYTES = BM * 128, BBYTES = BN * 128;
    constexpr int BBASE = 2 * ABYTES;
    __shared__ __align__(1024) char lds[2 * ABYTES + 2 * BBYTES];

    const int tid  = threadIdx.x;
    const int wave = tid >> 6, lane = tid & 63;
    const int wm = wave >> 2, wn = wave & 3;
    const int l15 = lane & 15, lhi = lane >> 4;

    // XCD-aware bijective swizzle (grid multiple of 8)
    const int nwg = gridDim.x;
    const int bid = blockIdx.x;
    const int wg  = (bid & 7) * (nwg >> 3) + (bid >> 3);
    constexpr int NBN = NOUT / BN;
    const int bm = wg / NBN, bn = wg % NBN;

    const __hip_bfloat16* gA = A  + (size_t)(bm * BM) * KD;
    const __hip_bfloat16* gB = BT + (size_t)(bn * BN) * KD;

    // staging: row=tid>>3, 16B chunk=tid&7; source chunk XOR-swizzled by row&7
    const int srow = tid >> 3;
    const int scol = ((tid & 7) ^ (srow & 7)) * 8;   // elements
    char* sd = lds + srow * 128 + (tid & 7) * 16;    // linear LDS dest

    const __hip_bfloat16* pA = gA + (size_t)srow * KD + scol;
    const __hip_bfloat16* pB = gB + (size_t)srow * KD + scol;

    // ---- prologue: B(0)->Bbuf0, A(0)->Abuf0, B(1)->Bbuf1
    #pragma unroll
    for (int s = 0; s < LB; ++s) gload_lds16(pB + (size_t)(s * 64) * KD,             sd + BBASE + s * 8192);
    #pragma unroll
    for (int s = 0; s < LB; ++s) gload_lds16(pB + (size_t)(BN/2 + s * 64) * KD,      sd + BBASE + (BN/2) * 128 + s * 8192);
    #pragma unroll
    for (int s = 0; s < LA; ++s) gload_lds16(pA + (size_t)(s * 64) * KD,             sd + s * 8192);
    #pragma unroll
    for (int s = 0; s < LA; ++s) gload_lds16(pA + (size_t)(BM/2 + s * 64) * KD,      sd + (BM/2) * 128 + s * 8192);
    #pragma unroll
    for (int s = 0; s < LB; ++s) gload_lds16(pB + 64 + (size_t)(s * 64) * KD,        sd + BBASE + BBYTES + s * 8192);
    #pragma unroll
    for (int s = 0; s < LB; ++s) gload_lds16(pB + 64 + (size_t)(BN/2 + s * 64) * KD, sd + BBASE + BBYTES + (BN/2) * 128 + s * 8192);
    pA += 64; pB += 128;
    asm volatile("s_waitcnt vmcnt(4)" ::: "memory");
    __builtin_amdgcn_s_barrier();

    // ---- invariant per-lane LDS read bases (swizzle folds to (l15&7)<<4)
    const int arow0 = wm * (BM / 2) + l15;
    const int brow0 = wn * (BN / 4) + l15;
    const int swz   = (l15 & 7) << 4;
    const int colX[2] = { (lhi * 16) ^ swz, (64 + lhi * 16) ^ swz };
    const char* rA = lds + arow0 * 128;
    const char* rB = lds + brow0 * 128;

    bf16x8 af[MH][2], bf0[NH][2], bf1[NH][2];
    f32x4 acc[MF][NF] = {};

    // pre-read aLO(0), bLO(0)
    #pragma unroll
    for (int m = 0; m < MH; ++m)
        #pragma unroll
        for (int kk = 0; kk < 2; ++kk)
            af[m][kk] = *(const bf16x8*)(rA + colX[kk] + m * 2048);
    #pragma unroll
    for (int n = 0; n < NH; ++n)
        #pragma unroll
        for (int kk = 0; kk < 2; ++kk)
            bf0[n][kk] = *(const bf16x8*)(rB + colX[kk] + (BBASE + n * 2048));

    auto body = [&](int t, auto bufc) {
        constexpr int BUF   = decltype(bufc)::value;
        constexpr int ABUF  = BUF * ABYTES;
        constexpr int ABUFo = (BUF ^ 1) * ABYTES;
        constexpr int BBUF  = BBASE + BUF * BBYTES;
        constexpr int BBUFo = BBASE + (BUF ^ 1) * BBYTES;

        // ---- P0: stage A0(t+1); MFMA q00; read bHI(t)   [no barrier]
        if (t + 1 < NT) {
            #pragma unroll
            for (int s = 0; s < LA; ++s)
                gload_lds16(pA + (size_t)(s * 64) * KD, sd + ABUFo + s * 8192);
        }
        __builtin_amdgcn_s_setprio(1);
        #pragma unroll
        for (int kk = 0; kk < 2; ++kk)
            #pragma unroll
            for (int m = 0; m < MH; ++m)
                #pragma unroll
                for (int n = 0; n < NH; ++n)
                    acc[m][n] = __builtin_amdgcn_mfma_f32_16x16x32_bf16(af[m][kk], bf0[n][kk], acc[m][n], 0, 0, 0);
        __builtin_amdgcn_s_setprio(0);
        #pragma unroll
        for (int n = 0; n < NH; ++n)
            #pragma unroll
            for (int kk = 0; kk < 2; ++kk)
                bf1[n][kk] = *(const bf16x8*)(rB + colX[kk] + (BBUF + (NH + n) * 2048));

        // ---- P1: stage A1(t+1); MFMA q01; read aHI(t); BARRIER
        if (t + 1 < NT) {
            #pragma unroll
            for (int s = 0; s < LA; ++s)
                gload_lds16(pA + (size_t)(BM/2 + s * 64) * KD, sd + ABUFo + (BM/2) * 128 + s * 8192);
        }
        __builtin_amdgcn_s_setprio(1);
        #pragma unroll
        for (int kk = 0; kk < 2; ++kk)
            #pragma unroll
            for (int m = 0; m < MH; ++m)
                #pragma unroll
                for (int n = 0; n < NH; ++n)
                    acc[m][NH + n] = __builtin_amdgcn_mfma_f32_16x16x32_bf16(af[m][kk], bf1[n][kk], acc[m][NH + n], 0, 0, 0);
        __builtin_amdgcn_s_setprio(0);
        #pragma unroll
        for (int m = 0; m < MH; ++m)
            #pragma unroll
            for (int kk = 0; kk < 2; ++kk)
                af[m][kk] = *(const bf16x8*)(rA + colX[kk] + (ABUF + (MH + m) * 2048));
        __builtin_amdgcn_s_barrier();

        // ---- P2: stage B0(t+2); MFMA q10   [no barrier]
        if (t + 2 < NT) {
            #pragma unroll
            for (int s = 0; s < LB; ++s)
                gload_lds16(pB + (size_t)(s * 64) * KD, sd + BBUF + s * 8192);
        }
        __builtin_amdgcn_s_setprio(1);
        #pragma unroll
        for (int kk = 0; kk < 2; ++kk)
            #pragma unroll
            for (int m = 0; m < MH; ++m)
                #pragma unroll
                for (int n = 0; n < NH; ++n)
                    acc[MH + m][n] = __builtin_amdgcn_mfma_f32_16x16x32_bf16(af[m][kk], bf0[n][kk], acc[MH + m][n], 0, 0, 0);
        __builtin_amdgcn_s_setprio(0);

        // ---- P3: stage B1(t+2); vmcnt; BARRIER;
        //          read bLO(t+1); MFMA q11; read aLO(t+1)
        if (t + 2 < NT) {
            #pragma unroll
            for (int s = 0; s < LB; ++s)
                gload_lds16(pB + (size_t)(BN/2 + s * 64) * KD, sd + BBUF + (BN/2) * 128 + s * 8192);
            asm volatile("s_waitcnt vmcnt(4)" ::: "memory");
        } else {
            asm volatile("s_waitcnt vmcnt(0)" ::: "memory");
        }
        __builtin_amdgcn_s_barrier();
        if (t + 1 < NT) {
            #pragma unroll
            for (int n = 0; n < NH; ++n)
                #pragma unroll
                for (int kk = 0; kk < 2; ++kk)
                    bf0[n][kk] = *(const bf16x8*)(rB + colX[kk] + (BBUFo + n * 2048));
        }
        __builtin_amdgcn_s_setprio(1);
        #pragma unroll
        for (int kk = 0; kk < 2; ++kk)
            #pragma unroll
            for (int m = 0; m < MH; ++m)
                #pragma unroll
                for (int n = 0; n < NH; ++n)
                    acc[MH + m][NH + n] = __builtin_amdgcn_mfma_f32_16x16x32_bf16(af[m][kk], bf1[n][kk], acc[MH + m][NH + n], 0, 0, 0);
        __builtin_amdgcn_s_setprio(0);
        if (t + 1 < NT) {
            #pragma unroll
            for (int m = 0; m < MH; ++m)
                #pragma unroll
                for (int kk = 0; kk < 2; ++kk)
                    af[m][kk] = *(const bf16x8*)(rA + colX[kk] + (ABUFo + m * 2048));
        }
        pA += 64; pB += 64;
    };

    for (int tt = 0; tt < NT; tt += 2) {
        body(tt,     ICt<0>{});
        body(tt + 1, ICt<1>{});
    }

    if constexpr (FUSED) {
        // acc frag n in {0,1} = s_j, frag n+2 = t_j (same lane/row/reg),
        // j = bn*128 + wn*32 + n*16 + l15 (W3 was PERM-transposed).
        const int crow0 = bm * BM + wm * (BM / 2) + lhi * 4;
        const int jbase = bn * (BN / 2) + wn * 32 + l15;
        #pragma unroll
        for (int m = 0; m < MF; ++m) {
            #pragma unroll
            for (int r = 0; r < 4; ++r) {
                const int row = crow0 + m * 16 + r;
                float ldp = 0.0f;
                #pragma unroll
                for (int n = 0; n < 2; ++n) {
                    const int j = jbase + n * 16;
                    float sval = acc[m][n][r]     + bias[j];
                    float tval = acc[m][n + 2][r] + bias[NHALF + j];
                    float a = 2.0f * fast_tanh(sval);
                    ldp += a;
                    float2 xv = *(const float2*)(xg + (size_t)row * LFULL + 2 * j);
                    float2 yv;
                    yv.x = xv.x;                       // even col: exact copy
                    yv.y = xv.y * __expf(a) + tval;    // odd col: affine update
                    *(float2*)(yg + (size_t)row * LFULL + 2 * j) = yv;
                }
                ldp += __shfl_xor(ldp, 1, 64);
                ldp += __shfl_xor(ldp, 2, 64);
                ldp += __shfl_xor(ldp, 4, 64);
                ldp += __shfl_xor(ldp, 8, 64);
                if (l15 == 0) atomicAdd(&ldg[row], ldp);
            }
        }
    } else {
        // ---- C write: col = lane&15 (+n*16), row = lhi*4 + r (+m*16)
        const int crow0 = bm * BM + wm * (BM / 2) + lhi * 4;
        const int ccol0 = bn * BN + wn * (BN / 4) + l15;
        #pragma unroll
        for (int m = 0; m < MF; ++m) {
            #pragma unroll
            for (int n = 0; n < NF; ++n) {
                int col = ccol0 + n * 16;
                float bv = bias[col];
                #pragma unroll
                for (int r = 0; r < 4; ++r) {
                    int row = crow0 + m * 16 + r;
                    float v = acc[m][n][r] + bv;
                    if (RELU) v = (v > 0.0f) ? v : 0.2f * v;
                    C[(size_t)row * NOUT + col] = __float2bfloat16(v);
                }
            }
        }
    }
}

// ---------------------------------------------------------------------------
extern "C" void kernel_launch(void* const* d_in, const int* in_sizes, int n_in,
                              void* d_out, int out_size, void* d_ws, size_t ws_size,
                              hipStream_t stream)
{
    const float* x  = (const float*)d_in[0];
    const float* W1 = (const float*)d_in[1];
    const float* b1 = (const float*)d_in[2];
    const float* W2 = (const float*)d_in[3];
    const float* b2 = (const float*)d_in[4];
    const float* W3 = (const float*)d_in[5];
    const float* b3 = (const float*)d_in[6];

    char* ws = (char*)d_ws;
    const size_t MB = 1u << 20;
    __hip_bfloat16* W3T  = (__hip_bfloat16*)(ws);              // 16 MB: 4096x2048 (PERM)
    __hip_bfloat16* h2   = (__hip_bfloat16*)(ws + 16 * MB);    // 16 MB: 4096x2048
    __hip_bfloat16* xmb  = (__hip_bfloat16*)(ws + 32 * MB);    // 16 MB
    __hip_bfloat16* W1T  = (__hip_bfloat16*)(ws + 48 * MB);    //  8 MB
    __hip_bfloat16* W2T  = (__hip_bfloat16*)(ws + 56 * MB);    //  8 MB
    __hip_bfloat16* h1   = (__hip_bfloat16*)(ws + 64 * MB);    // 16 MB

    float* y  = (float*)d_out;
    float* ld = y + (size_t)MROWS * LFULL;

    cast_x_kernel<<<4096, 256, 0, stream>>>(x, xmb, ld);
    transpose_cast_kernel<false><<<dim3(32, 32), 256, 0, stream>>>(W1, W1T, HDIM, HDIM);
    transpose_cast_kernel<false><<<dim3(32, 32), 256, 0, stream>>>(W2, W2T, HDIM, HDIM);
    transpose_cast_kernel<true ><<<dim3(64, 32), 256, 0, stream>>>(W3, W3T, HDIM, LFULL);

    gemm8p<128, 256, 2048, 2048, true,  false><<<dim3(256), dim3(512), 0, stream>>>(xmb, W1T, b1, h1, nullptr, nullptr, nullptr);
    gemm8p<128, 256, 2048, 2048, true,  false><<<dim3(256), dim3(512), 0, stream>>>(h1,  W2T, b2, h2, nullptr, nullptr, nullptr);
    gemm8p<256, 256, 2048, 4096, false, true ><<<dim3(256), dim3(512), 0, stream>>>(h2,  W3T, b3, nullptr, x, y, ld);
}